// Round 1
// baseline (316.085 us; speedup 1.0000x reference)
//
#include <hip/hip_runtime.h>

typedef unsigned short u16;
typedef short short8 __attribute__((ext_vector_type(8)));
typedef float floatx4 __attribute__((ext_vector_type(4)));
typedef u16 u16x4 __attribute__((ext_vector_type(4)));

#define DEVI __device__ __forceinline__

DEVI u16 f2bf(float x) {
    union { float f; unsigned u; } c; c.f = x;
    unsigned u = c.u;
    u += 0x7fffu + ((u >> 16) & 1u);   // RNE
    return (u16)(u >> 16);
}
DEVI float bf2f(u16 h) {
    union { unsigned u; float f; } c; c.u = ((unsigned)h) << 16;
    return c.f;
}

// async global->LDS, 16B per lane. LDS dest semantics: wave-uniform base + lane*16.
DEVI void gload_lds16(const void* g, void* l) {
    auto gp = (const __attribute__((address_space(1))) unsigned*)(unsigned long long)g;
    auto lp = (__attribute__((address_space(3))) unsigned*)(unsigned)(unsigned long long)l;
    __builtin_amdgcn_global_load_lds(gp, lp, 16, 0, 0);
}

// ---------------- GroupNorm ----------------
// stats per (b,g): group data is contiguous 16*1024 floats
__global__ __launch_bounds__(256) void gn_stats_kernel(const float* __restrict__ x,
                                                       float* __restrict__ stats) {
    const int bg = blockIdx.x;  // b*32+g
    const float4* p4 = (const float4*)(x + (long long)bg * 16384);
    float s = 0.f, s2 = 0.f;
    for (int i = threadIdx.x; i < 4096; i += 256) {
        float4 v = p4[i];
        s  += v.x + v.y + v.z + v.w;
        s2 += v.x*v.x + v.y*v.y + v.z*v.z + v.w*v.w;
    }
    __shared__ float rs[256], rq[256];
    rs[threadIdx.x] = s; rq[threadIdx.x] = s2;
    __syncthreads();
    for (int st = 128; st > 0; st >>= 1) {
        if (threadIdx.x < st) { rs[threadIdx.x] += rs[threadIdx.x+st]; rq[threadIdx.x] += rq[threadIdx.x+st]; }
        __syncthreads();
    }
    if (threadIdx.x == 0) {
        float mean = rs[0] * (1.f/16384.f);
        float var  = rq[0] * (1.f/16384.f) - mean*mean;
        stats[bg*2]   = mean;
        stats[bg*2+1] = rsqrtf(var + 1e-5f);
    }
}

// apply + transpose: x[b][c][n] fp32 -> h[b][n][c] bf16 (channel-last for TN GEMM)
__global__ __launch_bounds__(256) void gn_apply_kernel(const float* __restrict__ x,
                                                       const float* __restrict__ stats,
                                                       const float* __restrict__ w,
                                                       const float* __restrict__ bias,
                                                       u16* __restrict__ h) {
    const int b  = blockIdx.y;
    const int n0 = blockIdx.x * 32;
    const int t  = threadIdx.x;
    const int tx = t & 31, ty = t >> 5;  // 32 n-cols, 8 c-rows per pass
    __shared__ u16 lds[512][33];
    const float* xb = x + (long long)b * 512 * 1024;
    for (int cc = 0; cc < 512; cc += 8) {
        int c = cc + ty;
        int g = c >> 4;
        float mean = stats[(b*32+g)*2];
        float rstd = stats[(b*32+g)*2+1];
        float val  = xb[(long long)c*1024 + n0 + tx];
        lds[c][tx] = f2bf((val - mean) * rstd * w[c] + bias[c]);
    }
    __syncthreads();
    u16* hb = h + (long long)b * 1024 * 512;
    for (int idx = t; idx < 32*512; idx += 256) {
        int nl = idx >> 9;
        int c  = idx & 511;
        hb[(long long)(n0+nl)*512 + c] = lds[c][nl];
    }
}

// ---------------- fp32 -> bf16 weight convert ----------------
__global__ __launch_bounds__(256) void f2bf_kernel(const float* __restrict__ in,
                                                   u16* __restrict__ out, int n) {
    int i = blockIdx.x * 256 + threadIdx.x;
    if (i < n) out[i] = f2bf(in[i]);
}

// ---------------- transpose v: qkv[b][n][1024+c] -> vcn[b][c][n] ----------------
__global__ __launch_bounds__(256) void vtrans_kernel(const u16* __restrict__ qkv,
                                                     u16* __restrict__ vcn) {
    const int b  = blockIdx.z;
    const int n0 = blockIdx.x * 32;
    const int c0 = blockIdx.y * 32;
    const int t  = threadIdx.x;
    const int tx = t & 31, ty = t >> 5;
    __shared__ u16 tl[32][33];
    const u16* q = qkv + (long long)b * 1024 * 1536 + 1024;
    #pragma unroll
    for (int i = 0; i < 4; i++) {
        int n = n0 + ty + i*8;
        tl[ty + i*8][tx] = q[(long long)n*1536 + c0 + tx];
    }
    __syncthreads();
    u16* o = vcn + (long long)b * 512 * 1024;
    #pragma unroll
    for (int i = 0; i < 4; i++) {
        int c = c0 + ty + i*8;
        o[(long long)c*1024 + n0 + tx] = tl[tx][ty + i*8];
    }
}

// ---------------- softmax, in-place on bf16 rows of 1024 ----------------
__global__ __launch_bounds__(256) void softmax_kernel(u16* __restrict__ P) {
    u16* p = P + (long long)blockIdx.x * 1024;
    const int t = threadIdx.x;
    float v[4];
    #pragma unroll
    for (int k = 0; k < 4; k++) v[k] = bf2f(p[t + k*256]);
    __shared__ float red[256];
    float mx = fmaxf(fmaxf(v[0], v[1]), fmaxf(v[2], v[3]));
    red[t] = mx; __syncthreads();
    for (int s = 128; s > 0; s >>= 1) {
        if (t < s) red[t] = fmaxf(red[t], red[t+s]);
        __syncthreads();
    }
    mx = red[0]; __syncthreads();
    float sum = 0.f;
    #pragma unroll
    for (int k = 0; k < 4; k++) { v[k] = __expf(v[k] - mx); sum += v[k]; }
    red[t] = sum; __syncthreads();
    for (int s = 128; s > 0; s >>= 1) {
        if (t < s) red[t] += red[t+s];
        __syncthreads();
    }
    float inv = 1.f / red[0];
    #pragma unroll
    for (int k = 0; k < 4; k++) p[t + k*256] = f2bf(v[k] * inv);
}

// ---------------- m97-style TN GEMM ----------------
// C[M][Nn] = A[M][K] * Bt[Nn][K]^T, all bf16 in, fp32 accum.
// 128x128 block tile, 4 waves each 64x64 (4x4 of 16x16x32 MFMA), BK=32.
// TRANS_OUT: write Ct[n*ldc+m]; else C[m*ldc+n]. Optional bias[m], res (fp32, C layout), scale.
template <bool TRANS_OUT, bool BF16_OUT>
__global__ __launch_bounds__(256)
void gemm_bt_kernel(const u16* __restrict__ A, const u16* __restrict__ Bt,
                    void* __restrict__ Cv,
                    const float* __restrict__ bias, const float* __restrict__ res,
                    float scale, int lda, int ldb, int ldc,
                    long long sA, long long sB, long long sC, long long sR, int K) {
    const int t    = threadIdx.x;
    const int lane = t & 63;
    const int wave = t >> 6;
    const int m0   = blockIdx.y * 128;
    const int n0   = blockIdx.x * 128;
    const int z    = blockIdx.z;
    A  += (long long)z * sA;
    Bt += (long long)z * sB;

    __shared__ __align__(16) u16 As[128 * 32];
    __shared__ __align__(16) u16 Bs[128 * 32];

    const int wm = wave >> 1, wn = wave & 1;
    const int quad = lane >> 4, lrow = lane & 15;

    floatx4 acc[4][4];
    #pragma unroll
    for (int i = 0; i < 4; i++)
        #pragma unroll
        for (int j = 0; j < 4; j++)
            #pragma unroll
            for (int r = 0; r < 4; r++) acc[i][j][r] = 0.f;

    const int rowA = t >> 2;        // 0..63
    const int kch  = (t & 3) * 8;   // element offset in k
    const u16* Ag = A  + (long long)(m0 + rowA) * lda + kch;
    const u16* Bg = Bt + (long long)(n0 + rowA) * ldb + kch;
    u16* Al = &As[t * 8];
    u16* Bl = &Bs[t * 8];

    for (int k0 = 0; k0 < K; k0 += 32) {
        gload_lds16(Ag + k0, Al);
        gload_lds16(Ag + k0 + (long long)64 * lda, Al + 2048);
        gload_lds16(Bg + k0, Bl);
        gload_lds16(Bg + k0 + (long long)64 * ldb, Bl + 2048);
        __syncthreads();
        short8 af[4], bfr[4];
        #pragma unroll
        for (int i = 0; i < 4; i++)
            af[i] = *(const short8*)&As[(wm*64 + i*16 + lrow)*32 + quad*8];
        #pragma unroll
        for (int j = 0; j < 4; j++)
            bfr[j] = *(const short8*)&Bs[(wn*64 + j*16 + lrow)*32 + quad*8];
        #pragma unroll
        for (int i = 0; i < 4; i++)
            #pragma unroll
            for (int j = 0; j < 4; j++)
                acc[i][j] = __builtin_amdgcn_mfma_f32_16x16x32_bf16(af[i], bfr[j], acc[i][j], 0, 0, 0);
        __syncthreads();
    }

    const int mb = m0 + wm*64;
    const int nb = n0 + wn*64;
    if (TRANS_OUT) {
        u16* C = (u16*)Cv + (long long)z * sC;
        #pragma unroll
        for (int i = 0; i < 4; i++) {
            int mm = mb + i*16 + quad*4;
            #pragma unroll
            for (int j = 0; j < 4; j++) {
                int nn = nb + j*16 + lrow;
                u16x4 pk;
                #pragma unroll
                for (int r = 0; r < 4; r++) {
                    float v = acc[i][j][r] * scale;
                    if (bias) v += bias[mm + r];
                    pk[r] = f2bf(v);
                }
                *(u16x4*)&C[(long long)nn * ldc + mm] = pk;
            }
        }
    } else {
        const float* rz = res ? res + (long long)z * sR : nullptr;
        #pragma unroll
        for (int i = 0; i < 4; i++) {
            int mm = mb + i*16 + quad*4;
            #pragma unroll
            for (int j = 0; j < 4; j++) {
                int nn = nb + j*16 + lrow;
                #pragma unroll
                for (int r = 0; r < 4; r++) {
                    float v = acc[i][j][r] * scale;
                    if (bias) v += bias[mm + r];
                    long long idx = (long long)(mm + r) * ldc + nn;
                    if (rz) v += rz[idx];
                    if (BF16_OUT) ((u16*)Cv + (long long)z * sC)[idx] = f2bf(v);
                    else          ((float*)Cv + (long long)z * sC)[idx] = v;
                }
            }
        }
    }
}

extern "C" void kernel_launch(void* const* d_in, const int* in_sizes, int n_in,
                              void* d_out, int out_size, void* d_ws, size_t ws_size,
                              hipStream_t stream) {
    (void)in_sizes; (void)n_in; (void)out_size; (void)ws_size;
    const float* x     = (const float*)d_in[0];
    const float* gn_w  = (const float*)d_in[1];
    const float* gn_b  = (const float*)d_in[2];
    const float* qkv_w = (const float*)d_in[3];
    const float* qkv_b = (const float*)d_in[4];
    const float* out_w = (const float*)d_in[5];
    const float* out_b = (const float*)d_in[6];
    float* out = (float*)d_out;

    char* ws = (char*)d_ws;
    u16*  h_t   = (u16*)ws;  ws += (size_t)16*1024*512*2;    // 16 MB  h[b][n][c]
    u16*  qkv_t = (u16*)ws;  ws += (size_t)16*1024*1536*2;   // 48 MB  qkv[b][n][o]
    u16*  v_cn  = (u16*)ws;  ws += (size_t)16*512*1024*2;    // 16 MB  v[b][c][n]
    u16*  S     = (u16*)ws;  ws += (size_t)16*1024*1024*2;   // 32 MB  S/P[b][n][m]
    u16*  O     = (u16*)ws;  ws += (size_t)16*1024*512*2;    // 16 MB  O[b][n][c]
    float* stats = (float*)ws; ws += (size_t)512*2*4;
    u16*  wq    = (u16*)ws;  ws += (size_t)1536*512*2;
    u16*  wo    = (u16*)ws;  ws += (size_t)512*512*2;

    f2bf_kernel<<<(1536*512 + 255)/256, 256, 0, stream>>>(qkv_w, wq, 1536*512);
    f2bf_kernel<<<(512*512 + 255)/256, 256, 0, stream>>>(out_w, wo, 512*512);
    gn_stats_kernel<<<512, 256, 0, stream>>>(x, stats);
    gn_apply_kernel<<<dim3(32, 16), 256, 0, stream>>>(x, stats, gn_w, gn_b, h_t);

    // QKV: M=1536, Nn=16384, K=512 ; out transposed -> qkv_t[b*N+n][o], +qkv_b
    gemm_bt_kernel<true, true><<<dim3(128, 12, 1), 256, 0, stream>>>(
        wq, h_t, qkv_t, qkv_b, nullptr, 1.0f,
        512, 512, 1536, 0, 0, 0, 0, 512);

    vtrans_kernel<<<dim3(32, 16, 16), 256, 0, stream>>>(qkv_t, v_cn);

    // S = q k^T * scale : per batch M=Nn=1024, K=512; A rows = q (cols 0..512), Bt rows = k (cols 512..1024)
    gemm_bt_kernel<false, true><<<dim3(8, 8, 16), 256, 0, stream>>>(
        qkv_t, qkv_t + 512, S, nullptr, nullptr, 0.044194173824159216f,
        1536, 1536, 1024,
        (long long)1024*1536, (long long)1024*1536, (long long)1024*1024, 0, 512);

    softmax_kernel<<<16384, 256, 0, stream>>>(S);

    // O = P @ v^T : M=1024(n), Nn=512(c), K=1024(m)
    gemm_bt_kernel<false, true><<<dim3(4, 8, 16), 256, 0, stream>>>(
        S, v_cn, O, nullptr, nullptr, 1.0f,
        1024, 1024, 512,
        (long long)1024*1024, (long long)512*1024, (long long)1024*512, 0, 1024);

    // out = out_w @ O^T + out_b + x : M=512(co), Nn=1024(n), K=512(ci)
    gemm_bt_kernel<false, false><<<dim3(8, 4, 16), 256, 0, stream>>>(
        wo, O, out, out_b, x, 1.0f,
        512, 512, 1024,
        0, (long long)1024*512, (long long)512*1024, (long long)512*1024, 512);
}

// Round 2
// 296.513 us; speedup vs baseline: 1.0660x; 1.0660x over previous
//
#include <hip/hip_runtime.h>

typedef unsigned short u16;
typedef short short8 __attribute__((ext_vector_type(8)));
typedef float floatx4 __attribute__((ext_vector_type(4)));
typedef u16 u16x4 __attribute__((ext_vector_type(4)));
typedef u16 u16x8 __attribute__((ext_vector_type(8)));

#define DEVI __device__ __forceinline__

DEVI u16 f2bf(float x) {
    union { float f; unsigned u; } c; c.f = x;
    unsigned u = c.u;
    u += 0x7fffu + ((u >> 16) & 1u);   // RNE
    return (u16)(u >> 16);
}
DEVI float bf2f(u16 h) {
    union { unsigned u; float f; } c; c.u = ((unsigned)h) << 16;
    return c.f;
}

// async global->LDS, 16B per lane. LDS dest semantics: wave-uniform base + lane*16.
DEVI void gload_lds16(const void* g, void* l) {
    auto gp = (const __attribute__((address_space(1))) unsigned*)(unsigned long long)g;
    auto lp = (__attribute__((address_space(3))) unsigned*)(unsigned)(unsigned long long)l;
    __builtin_amdgcn_global_load_lds(gp, lp, 16, 0, 0);
}

// ---------------- GroupNorm ----------------
__global__ __launch_bounds__(256) void gn_stats_kernel(const float* __restrict__ x,
                                                       float* __restrict__ stats) {
    const int bg = blockIdx.x;  // b*32+g
    const float4* p4 = (const float4*)(x + (long long)bg * 16384);
    float s = 0.f, s2 = 0.f;
    for (int i = threadIdx.x; i < 4096; i += 256) {
        float4 v = p4[i];
        s  += v.x + v.y + v.z + v.w;
        s2 += v.x*v.x + v.y*v.y + v.z*v.z + v.w*v.w;
    }
    __shared__ float rs[256], rq[256];
    rs[threadIdx.x] = s; rq[threadIdx.x] = s2;
    __syncthreads();
    for (int st = 128; st > 0; st >>= 1) {
        if (threadIdx.x < st) { rs[threadIdx.x] += rs[threadIdx.x+st]; rq[threadIdx.x] += rq[threadIdx.x+st]; }
        __syncthreads();
    }
    if (threadIdx.x == 0) {
        float mean = rs[0] * (1.f/16384.f);
        float var  = rq[0] * (1.f/16384.f) - mean*mean;
        stats[bg*2]   = mean;
        stats[bg*2+1] = rsqrtf(var + 1e-5f);
    }
}

// apply + transpose: x[b][c][n] fp32 -> h[b][n][c] bf16
__global__ __launch_bounds__(256) void gn_apply_kernel(const float* __restrict__ x,
                                                       const float* __restrict__ stats,
                                                       const float* __restrict__ w,
                                                       const float* __restrict__ bias,
                                                       u16* __restrict__ h) {
    const int b  = blockIdx.y;
    const int n0 = blockIdx.x * 32;
    const int t  = threadIdx.x;
    const int tx = t & 31, ty = t >> 5;
    __shared__ u16 lds[512][33];
    const float* xb = x + (long long)b * 512 * 1024;
    for (int cc = 0; cc < 512; cc += 8) {
        int c = cc + ty;
        int g = c >> 4;
        float mean = stats[(b*32+g)*2];
        float rstd = stats[(b*32+g)*2+1];
        float val  = xb[(long long)c*1024 + n0 + tx];
        lds[c][tx] = f2bf((val - mean) * rstd * w[c] + bias[c]);
    }
    __syncthreads();
    u16* hb = h + (long long)b * 1024 * 512;
    // u16x4 writes: 32 n rows x 128 chunks
    for (int idx = t; idx < 32*128; idx += 256) {
        int nl = idx >> 7;
        int c4 = (idx & 127) * 4;
        u16x4 pk;
        #pragma unroll
        for (int k = 0; k < 4; k++) pk[k] = lds[c4 + k][nl];
        *(u16x4*)&hb[(long long)(n0+nl)*512 + c4] = pk;
    }
}

__global__ __launch_bounds__(256) void f2bf_kernel(const float* __restrict__ in,
                                                   u16* __restrict__ out, int n) {
    int i = blockIdx.x * 256 + threadIdx.x;
    if (i < n) out[i] = f2bf(in[i]);
}

// ---------------- softmax: one wave per row of 1024, vectorized ----------------
__global__ __launch_bounds__(256) void softmax_kernel(u16* __restrict__ P) {
    const int wave = threadIdx.x >> 6, lane = threadIdx.x & 63;
    const long long row = (long long)blockIdx.x * 4 + wave;
    u16* p = P + row * 1024 + lane * 16;
    u16x8 a = *(u16x8*)p;
    u16x8 b = *(u16x8*)(p + 8);
    float v[16];
    #pragma unroll
    for (int k = 0; k < 8; k++) { v[k] = bf2f(a[k]); v[8+k] = bf2f(b[k]); }
    float mx = v[0];
    #pragma unroll
    for (int k = 1; k < 16; k++) mx = fmaxf(mx, v[k]);
    #pragma unroll
    for (int m = 1; m < 64; m <<= 1) mx = fmaxf(mx, __shfl_xor(mx, m, 64));
    float s = 0.f;
    #pragma unroll
    for (int k = 0; k < 16; k++) { v[k] = __expf(v[k] - mx); s += v[k]; }
    #pragma unroll
    for (int m = 1; m < 64; m <<= 1) s += __shfl_xor(s, m, 64);
    float inv = 1.f / s;
    #pragma unroll
    for (int k = 0; k < 8; k++) { a[k] = f2bf(v[k]*inv); b[k] = f2bf(v[8+k]*inv); }
    *(u16x8*)p = a;
    *(u16x8*)(p + 8) = b;
}

// ---------------- m97-style TN GEMM with LDS-staged coalesced epilogues ----------------
// C = A[M][K] * Bt[Nn][K]^T, bf16 in, fp32 accum. 128x128 tile, 4 waves, BK=32.
// MODE 0: fp32 out + bias + residual (C0, res fp32, C layout [m][n])
// MODE 1: bf16 out, scaled, no bias (C0, [m][n])
// MODE 2: QKV split: m0<1024 -> transposed bf16 to C0[n][m] (ldc=1024) + bias;
//                    m0>=1024 -> bf16 to C1[(m-1024)][n] (ld=16384) + bias.
template <int MODE>
__global__ __launch_bounds__(256)
void gemm_bt_kernel(const u16* __restrict__ A, const u16* __restrict__ Bt,
                    void* __restrict__ C0, void* __restrict__ C1,
                    const float* __restrict__ bias, const float* __restrict__ res,
                    float scale, int lda, int ldb, int ldc,
                    long long sA, long long sB, long long sC, long long sR, int K) {
    const int t    = threadIdx.x;
    const int lane = t & 63;
    const int wave = t >> 6;
    const int m0   = blockIdx.y * 128;
    const int n0   = blockIdx.x * 128;
    const int z    = blockIdx.z;
    A  += (long long)z * sA;
    Bt += (long long)z * sB;

    __shared__ __align__(16) u16 smem[17408];   // 34816 B; K-loop uses first 16 KB
    u16* As = smem;
    u16* Bs = smem + 4096;

    const int wm = wave >> 1, wn = wave & 1;
    const int quad = lane >> 4, lrow = lane & 15;

    floatx4 acc[4][4];
    #pragma unroll
    for (int i = 0; i < 4; i++)
        #pragma unroll
        for (int j = 0; j < 4; j++)
            #pragma unroll
            for (int r = 0; r < 4; r++) acc[i][j][r] = 0.f;

    const int rowA = t >> 2;
    const int kch  = (t & 3) * 8;
    const u16* Ag = A  + (long long)(m0 + rowA) * lda + kch;
    const u16* Bg = Bt + (long long)(n0 + rowA) * ldb + kch;
    u16* Al = &As[t * 8];
    u16* Bl = &Bs[t * 8];

    for (int k0 = 0; k0 < K; k0 += 32) {
        gload_lds16(Ag + k0, Al);
        gload_lds16(Ag + k0 + (long long)64 * lda, Al + 2048);
        gload_lds16(Bg + k0, Bl);
        gload_lds16(Bg + k0 + (long long)64 * ldb, Bl + 2048);
        __syncthreads();
        short8 af[4], bfr[4];
        #pragma unroll
        for (int i = 0; i < 4; i++)
            af[i] = *(const short8*)&As[(wm*64 + i*16 + lrow)*32 + quad*8];
        #pragma unroll
        for (int j = 0; j < 4; j++)
            bfr[j] = *(const short8*)&Bs[(wn*64 + j*16 + lrow)*32 + quad*8];
        #pragma unroll
        for (int i = 0; i < 4; i++)
            #pragma unroll
            for (int j = 0; j < 4; j++)
                acc[i][j] = __builtin_amdgcn_mfma_f32_16x16x32_bf16(af[i], bfr[j], acc[i][j], 0, 0, 0);
        __syncthreads();
    }
    // after this barrier smem is free for the epilogue

    const int ST = 136;  // u16 stride: 272 B = 17*16 -> 16B-aligned rows, <=2-way banks

    if (MODE == 1) {
        #pragma unroll
        for (int i = 0; i < 4; i++) {
            int rB = wm*64 + i*16 + quad*4;
            #pragma unroll
            for (int j = 0; j < 4; j++) {
                int cB = wn*64 + j*16 + lrow;
                #pragma unroll
                for (int r = 0; r < 4; r++)
                    smem[(rB + r)*ST + cB] = f2bf(acc[i][j][r] * scale);
            }
        }
        __syncthreads();
        u16* C = (u16*)C0 + (long long)z * sC;
        const int rr = t >> 1, hh = (t & 1) * 64;
        #pragma unroll
        for (int p2 = 0; p2 < 8; p2++)
            *(u16x8*)&C[(long long)(m0+rr)*ldc + n0 + hh + p2*8] =
                *(u16x8*)&smem[rr*ST + hh + p2*8];
    } else if (MODE == 2) {
        if (m0 < 1024) {
            // transposed: smem[n_local][m_local], pack r along m
            #pragma unroll
            for (int i = 0; i < 4; i++) {
                int mmL = wm*64 + i*16 + quad*4;
                #pragma unroll
                for (int j = 0; j < 4; j++) {
                    int nnL = wn*64 + j*16 + lrow;
                    u16x4 pk;
                    #pragma unroll
                    for (int r = 0; r < 4; r++)
                        pk[r] = f2bf(acc[i][j][r] + bias[m0 + mmL + r]);
                    *(u16x4*)&smem[nnL*ST + mmL] = pk;
                }
            }
            __syncthreads();
            u16* C = (u16*)C0;
            const int rr = t >> 1, hh = (t & 1) * 64;
            const long long bn = n0 + rr;
            #pragma unroll
            for (int p2 = 0; p2 < 8; p2++)
                *(u16x8*)&C[bn*1024 + m0 + hh + p2*8] =
                    *(u16x8*)&smem[rr*ST + hh + p2*8];
        } else {
            #pragma unroll
            for (int i = 0; i < 4; i++) {
                int rB = wm*64 + i*16 + quad*4;
                #pragma unroll
                for (int j = 0; j < 4; j++) {
                    int cB = wn*64 + j*16 + lrow;
                    #pragma unroll
                    for (int r = 0; r < 4; r++)
                        smem[(rB + r)*ST + cB] = f2bf(acc[i][j][r] + bias[m0 + rB + r]);
                }
            }
            __syncthreads();
            u16* C = (u16*)C1;
            const int rr = t >> 1, hh = (t & 1) * 64;
            #pragma unroll
            for (int p2 = 0; p2 < 8; p2++)
                *(u16x8*)&C[(long long)(m0 - 1024 + rr)*16384 + n0 + hh + p2*8] =
                    *(u16x8*)&smem[rr*ST + hh + p2*8];
        }
    } else {  // MODE 0: fp32 + bias + residual, two half-tile passes
        float* smf = (float*)smem;
        const int SF = 132;  // float stride: 528 B = 33*16
        float* C = (float*)C0 + (long long)z * sC;
        const float* rz = res + (long long)z * sR;
        #pragma unroll
        for (int pass = 0; pass < 2; pass++) {
            if (pass) __syncthreads();
            if (wm == pass) {
                #pragma unroll
                for (int i = 0; i < 4; i++) {
                    int rL = i*16 + quad*4;
                    #pragma unroll
                    for (int j = 0; j < 4; j++) {
                        int cB = wn*64 + j*16 + lrow;
                        #pragma unroll
                        for (int r = 0; r < 4; r++)
                            smf[(rL + r)*SF + cB] = acc[i][j][r] + bias[m0 + pass*64 + rL + r];
                    }
                }
            }
            __syncthreads();
            const int rr = t >> 2, qq = (t & 3) * 32;
            const int gr = m0 + pass*64 + rr;
            #pragma unroll
            for (int p2 = 0; p2 < 8; p2++) {
                int cc = qq + p2*4;
                float4 rv = *(const float4*)&rz[(long long)gr*ldc + n0 + cc];
                float4 ov;
                ov.x = smf[rr*SF + cc + 0] + rv.x;
                ov.y = smf[rr*SF + cc + 1] + rv.y;
                ov.z = smf[rr*SF + cc + 2] + rv.z;
                ov.w = smf[rr*SF + cc + 3] + rv.w;
                *(float4*)&C[(long long)gr*ldc + n0 + cc] = ov;
            }
        }
    }
}

extern "C" void kernel_launch(void* const* d_in, const int* in_sizes, int n_in,
                              void* d_out, int out_size, void* d_ws, size_t ws_size,
                              hipStream_t stream) {
    (void)in_sizes; (void)n_in; (void)out_size; (void)ws_size;
    const float* x     = (const float*)d_in[0];
    const float* gn_w  = (const float*)d_in[1];
    const float* gn_b  = (const float*)d_in[2];
    const float* qkv_w = (const float*)d_in[3];
    const float* qkv_b = (const float*)d_in[4];
    const float* out_w = (const float*)d_in[5];
    const float* out_b = (const float*)d_in[6];
    float* out = (float*)d_out;

    char* ws = (char*)d_ws;
    u16*  h_t   = (u16*)ws;  ws += (size_t)16*1024*512*2;    // 16 MB  h[b][n][c]
    u16*  qkv_t = (u16*)ws;  ws += (size_t)16*1024*1024*2;   // 32 MB  qk[b][n][0..1023]
    u16*  v2    = (u16*)ws;  ws += (size_t)512*16384*2;      // 16 MB  v[c][b*1024+n]
    u16*  S     = (u16*)ws;  ws += (size_t)16*1024*1024*2;   // 32 MB  S/P[b][n][m]
    u16*  O     = (u16*)ws;  ws += (size_t)16*1024*512*2;    // 16 MB  O[b][n][c]
    float* stats = (float*)ws; ws += (size_t)512*2*4;
    u16*  wq    = (u16*)ws;  ws += (size_t)1536*512*2;
    u16*  wo    = (u16*)ws;  ws += (size_t)512*512*2;

    f2bf_kernel<<<(1536*512 + 255)/256, 256, 0, stream>>>(qkv_w, wq, 1536*512);
    f2bf_kernel<<<(512*512 + 255)/256, 256, 0, stream>>>(out_w, wo, 512*512);
    gn_stats_kernel<<<512, 256, 0, stream>>>(x, stats);
    gn_apply_kernel<<<dim3(32, 16), 256, 0, stream>>>(x, stats, gn_w, gn_b, h_t);

    // QKV: M=1536, Nn=16384, K=512; q,k -> qkv_t[bn][m] transposed; v -> v2[c][bn]
    gemm_bt_kernel<2><<<dim3(128, 12, 1), 256, 0, stream>>>(
        wq, h_t, qkv_t, v2, qkv_b, nullptr, 1.0f,
        512, 512, 1024, 0, 0, 0, 0, 512);

    // S = q k^T * scale : per batch M=Nn=1024, K=512
    gemm_bt_kernel<1><<<dim3(8, 8, 16), 256, 0, stream>>>(
        qkv_t, qkv_t + 512, S, nullptr, nullptr, nullptr, 0.044194173824159216f,
        1024, 1024, 1024,
        (long long)1024*1024, (long long)1024*1024, (long long)1024*1024, 0, 512);

    softmax_kernel<<<4096, 256, 0, stream>>>(S);

    // O = P @ V : M=1024(n), Nn=512(c), K=1024(m); Bt = v2 (ldb 16384, per-batch col offset)
    gemm_bt_kernel<1><<<dim3(4, 8, 16), 256, 0, stream>>>(
        S, v2, O, nullptr, nullptr, nullptr, 1.0f,
        1024, 16384, 512,
        (long long)1024*1024, 1024, (long long)1024*512, 0, 1024);

    // out = out_w @ O^T + out_b + x : M=512(co), Nn=1024(n), K=512(ci), fp32 + residual
    gemm_bt_kernel<0><<<dim3(8, 4, 16), 256, 0, stream>>>(
        wo, O, out, nullptr, out_b, x, 1.0f,
        512, 512, 1024,
        0, (long long)1024*512, (long long)512*1024, (long long)512*1024, 512);
}

// Round 3
// 268.603 us; speedup vs baseline: 1.1768x; 1.1039x over previous
//
#include <hip/hip_runtime.h>

typedef unsigned short u16;
typedef short short8 __attribute__((ext_vector_type(8)));
typedef float floatx4 __attribute__((ext_vector_type(4)));
typedef u16 u16x4 __attribute__((ext_vector_type(4)));
typedef u16 u16x8 __attribute__((ext_vector_type(8)));

#define DEVI __device__ __forceinline__

DEVI u16 f2bf(float x) {
    union { float f; unsigned u; } c; c.f = x;
    unsigned u = c.u;
    u += 0x7fffu + ((u >> 16) & 1u);   // RNE
    return (u16)(u >> 16);
}
DEVI float bf2f(u16 h) {
    union { unsigned u; float f; } c; c.u = ((unsigned)h) << 16;
    return c.f;
}

DEVI void gload_lds16(const void* g, void* l) {
    auto gp = (const __attribute__((address_space(1))) unsigned*)(unsigned long long)g;
    auto lp = (__attribute__((address_space(3))) unsigned*)(unsigned)(unsigned long long)l;
    __builtin_amdgcn_global_load_lds(gp, lp, 16, 0, 0);
}

// ---------------- fused GroupNorm: stats + apply + transpose ----------------
// one block per (b,g); x[b][g*16..][:] -> h[b][n][g*16..] bf16
__global__ __launch_bounds__(256) void gn_fused_kernel(const float* __restrict__ x,
                                                       const float* __restrict__ w,
                                                       const float* __restrict__ bb,
                                                       u16* __restrict__ h) {
    const int bg = blockIdx.x;           // b*32+g
    const int b = bg >> 5, g = bg & 31;
    const float* xg = x + (long long)bg * 16384;
    const float4* p4 = (const float4*)xg;
    float s = 0.f, s2 = 0.f;
    #pragma unroll
    for (int i = 0; i < 16; i++) {
        float4 v = p4[threadIdx.x + i * 256];
        s  += v.x + v.y + v.z + v.w;
        s2 += v.x*v.x + v.y*v.y + v.z*v.z + v.w*v.w;
    }
    #pragma unroll
    for (int m = 1; m < 64; m <<= 1) { s += __shfl_xor(s, m, 64); s2 += __shfl_xor(s2, m, 64); }
    __shared__ float rs[4], rq[4];
    if ((threadIdx.x & 63) == 0) { rs[threadIdx.x >> 6] = s; rq[threadIdx.x >> 6] = s2; }
    __syncthreads();
    float mean = (rs[0] + rs[1] + rs[2] + rs[3]) * (1.f / 16384.f);
    float var  = (rq[0] + rq[1] + rq[2] + rq[3]) * (1.f / 16384.f) - mean * mean;
    float rstd = rsqrtf(var + 1e-5f);

    float sc[16], sh[16];
    #pragma unroll
    for (int cc = 0; cc < 16; cc++) {
        int c = g * 16 + cc;
        sc[cc] = w[c] * rstd;
        sh[cc] = bb[c] - mean * sc[cc];
    }
    const int n0 = threadIdx.x * 4;
    u16x8 o[4][2];
    #pragma unroll
    for (int cc = 0; cc < 16; cc++) {
        float4 xv = *(const float4*)&xg[cc * 1024 + n0];   // L2-hot re-read
        o[0][cc >> 3][cc & 7] = f2bf(xv.x * sc[cc] + sh[cc]);
        o[1][cc >> 3][cc & 7] = f2bf(xv.y * sc[cc] + sh[cc]);
        o[2][cc >> 3][cc & 7] = f2bf(xv.z * sc[cc] + sh[cc]);
        o[3][cc >> 3][cc & 7] = f2bf(xv.w * sc[cc] + sh[cc]);
    }
    u16* hb = h + ((long long)b * 1024 + n0) * 512 + g * 16;
    #pragma unroll
    for (int k = 0; k < 4; k++) {
        *(u16x8*)&hb[(long long)k * 512]     = o[k][0];
        *(u16x8*)&hb[(long long)k * 512 + 8] = o[k][1];
    }
}

__global__ __launch_bounds__(256) void f2bf_kernel(const float* __restrict__ in,
                                                   u16* __restrict__ out, int n) {
    int i = blockIdx.x * 256 + threadIdx.x;
    if (i < n) out[i] = f2bf(in[i]);
}

// ---------------- softmax: one wave per row of 1024 ----------------
__global__ __launch_bounds__(256) void softmax_kernel(u16* __restrict__ P) {
    const int wave = threadIdx.x >> 6, lane = threadIdx.x & 63;
    const long long row = (long long)blockIdx.x * 4 + wave;
    u16* p = P + row * 1024 + lane * 16;
    u16x8 a = *(u16x8*)p;
    u16x8 b = *(u16x8*)(p + 8);
    float v[16];
    #pragma unroll
    for (int k = 0; k < 8; k++) { v[k] = bf2f(a[k]); v[8+k] = bf2f(b[k]); }
    float mx = v[0];
    #pragma unroll
    for (int k = 1; k < 16; k++) mx = fmaxf(mx, v[k]);
    #pragma unroll
    for (int m = 1; m < 64; m <<= 1) mx = fmaxf(mx, __shfl_xor(mx, m, 64));
    float s = 0.f;
    #pragma unroll
    for (int k = 0; k < 16; k++) { v[k] = __expf(v[k] - mx); s += v[k]; }
    #pragma unroll
    for (int m = 1; m < 64; m <<= 1) s += __shfl_xor(s, m, 64);
    float inv = 1.f / s;
    #pragma unroll
    for (int k = 0; k < 8; k++) { a[k] = f2bf(v[k]*inv); b[k] = f2bf(v[8+k]*inv); }
    *(u16x8*)p = a;
    *(u16x8*)(p + 8) = b;
}

// ---------------- TN GEMM, 128x128 tile, chunked LDS-staged epilogues ----------------
// MODE 0: fp32 out + bias + residual ([m][n])
// MODE 1: bf16 out, scaled ([m][n])
// MODE 2: QKV split: m0<1024 -> transposed bf16 C0[n][m] (+bias); else bf16 C1[(m-1024)][n] ld 16384 (+bias)
template <int MODE>
__global__ __launch_bounds__(256)
void gemm_bt_kernel(const u16* __restrict__ A, const u16* __restrict__ Bt,
                    void* __restrict__ C0, void* __restrict__ C1,
                    const float* __restrict__ bias, const float* __restrict__ res,
                    float scale, int lda, int ldb, int ldc,
                    long long sA, long long sB, long long sC, long long sR, int K) {
    const int t    = threadIdx.x;
    const int lane = t & 63;
    const int wave = t >> 6;
    const int m0   = blockIdx.y * 128;
    const int n0   = blockIdx.x * 128;
    const int z    = blockIdx.z;
    A  += (long long)z * sA;
    Bt += (long long)z * sB;

    __shared__ __align__(16) u16 smem[8192];   // 16 KB: K-loop A|B, then epilogue staging
    u16* As = smem;
    u16* Bs = smem + 4096;

    const int wm = wave >> 1, wn = wave & 1;
    const int quad = lane >> 4, lrow = lane & 15;

    floatx4 acc[4][4];
    #pragma unroll
    for (int i = 0; i < 4; i++)
        #pragma unroll
        for (int j = 0; j < 4; j++)
            #pragma unroll
            for (int r = 0; r < 4; r++) acc[i][j][r] = 0.f;

    const int rowA = t >> 2;
    const int kch  = (t & 3) * 8;
    const u16* Ag = A  + (long long)(m0 + rowA) * lda + kch;
    const u16* Bg = Bt + (long long)(n0 + rowA) * ldb + kch;
    u16* Al = &As[t * 8];
    u16* Bl = &Bs[t * 8];

    for (int k0 = 0; k0 < K; k0 += 32) {
        gload_lds16(Ag + k0, Al);
        gload_lds16(Ag + k0 + (long long)64 * lda, Al + 2048);
        gload_lds16(Bg + k0, Bl);
        gload_lds16(Bg + k0 + (long long)64 * ldb, Bl + 2048);
        __syncthreads();
        short8 af[4], bfr[4];
        #pragma unroll
        for (int i = 0; i < 4; i++)
            af[i] = *(const short8*)&As[(wm*64 + i*16 + lrow)*32 + quad*8];
        #pragma unroll
        for (int j = 0; j < 4; j++)
            bfr[j] = *(const short8*)&Bs[(wn*64 + j*16 + lrow)*32 + quad*8];
        #pragma unroll
        for (int i = 0; i < 4; i++)
            #pragma unroll
            for (int j = 0; j < 4; j++)
                acc[i][j] = __builtin_amdgcn_mfma_f32_16x16x32_bf16(af[i], bfr[j], acc[i][j], 0, 0, 0);
        __syncthreads();
    }
    // smem free from here

    const int ST = 136;  // u16 row stride (272 B = 17*16)

    if (MODE == 1 || (MODE == 2 && m0 >= 1024)) {
        // bf16 [m][n]-style output in 4 chunks of 32 rows (8.7 KB each)
        #pragma unroll
        for (int p = 0; p < 4; p++) {
            if (p) __syncthreads();
            if (wm == (p >> 1)) {
                #pragma unroll
                for (int ii = 0; ii < 2; ii++) {
                    const int i = (p & 1) * 2 + ii;
                    const int row = ii * 16 + quad * 4;
                    #pragma unroll
                    for (int j = 0; j < 4; j++) {
                        const int cB = wn * 64 + j * 16 + lrow;
                        #pragma unroll
                        for (int r = 0; r < 4; r++) {
                            float v = acc[i][j][r] * (MODE == 1 ? scale : 1.0f);
                            if (MODE == 2) v += bias[m0 + p * 32 + row + r];
                            smem[(row + r) * ST + cB] = f2bf(v);
                        }
                    }
                }
            }
            __syncthreads();
            const int rr = t >> 3, cc = (t & 7) * 16;
            u16x8 a0 = *(u16x8*)&smem[rr * ST + cc];
            u16x8 a1 = *(u16x8*)&smem[rr * ST + cc + 8];
            u16* Cp;
            if (MODE == 1)
                Cp = (u16*)C0 + (long long)z * sC + (long long)(m0 + p * 32 + rr) * ldc + n0 + cc;
            else
                Cp = (u16*)C1 + (long long)(m0 - 1024 + p * 32 + rr) * 16384 + n0 + cc;
            *(u16x8*)Cp = a0;
            *(u16x8*)(Cp + 8) = a1;
        }
    } else if (MODE == 2) {
        // transposed bf16: C0[n][m], 4 chunks of 32 n-rows
        #pragma unroll
        for (int p = 0; p < 4; p++) {
            if (p) __syncthreads();
            if (wn == (p >> 1)) {
                #pragma unroll
                for (int jj = 0; jj < 2; jj++) {
                    const int j = (p & 1) * 2 + jj;
                    const int row = jj * 16 + lrow;
                    #pragma unroll
                    for (int i = 0; i < 4; i++) {
                        const int mmL = wm * 64 + i * 16 + quad * 4;
                        u16x4 pk;
                        #pragma unroll
                        for (int r = 0; r < 4; r++)
                            pk[r] = f2bf(acc[i][j][r] + bias[m0 + mmL + r]);
                        *(u16x4*)&smem[row * ST + mmL] = pk;
                    }
                }
            }
            __syncthreads();
            const int rr = t >> 3, cc = (t & 7) * 16;
            u16x8 a0 = *(u16x8*)&smem[rr * ST + cc];
            u16x8 a1 = *(u16x8*)&smem[rr * ST + cc + 8];
            u16* Cp = (u16*)C0 + (long long)(n0 + p * 32 + rr) * 1024 + m0 + cc;
            *(u16x8*)Cp = a0;
            *(u16x8*)(Cp + 8) = a1;
        }
    } else {
        // MODE 0: fp32 + bias + residual, 8 chunks of 16 rows
        float* smf = (float*)smem;
        const int SF = 132;   // 16*132*4 = 8448 B
        float* C = (float*)C0 + (long long)z * sC;
        const float* rz = res + (long long)z * sR;
        #pragma unroll
        for (int p = 0; p < 8; p++) {
            if (p) __syncthreads();
            if (wm == (p >> 2)) {
                const int i = p & 3;
                #pragma unroll
                for (int j = 0; j < 4; j++) {
                    const int cB = wn * 64 + j * 16 + lrow;
                    #pragma unroll
                    for (int r = 0; r < 4; r++)
                        smf[(quad * 4 + r) * SF + cB] =
                            acc[i][j][r] + bias[m0 + p * 16 + quad * 4 + r];
                }
            }
            __syncthreads();
            const int rr = t >> 4, cc = (t & 15) * 8;
            const long long gro = (long long)(m0 + p * 16 + rr) * ldc + n0 + cc;
            float4 rv0 = *(const float4*)&rz[gro];
            float4 rv1 = *(const float4*)&rz[gro + 4];
            float4 ov0, ov1;
            ov0.x = smf[rr*SF + cc + 0] + rv0.x;
            ov0.y = smf[rr*SF + cc + 1] + rv0.y;
            ov0.z = smf[rr*SF + cc + 2] + rv0.z;
            ov0.w = smf[rr*SF + cc + 3] + rv0.w;
            ov1.x = smf[rr*SF + cc + 4] + rv1.x;
            ov1.y = smf[rr*SF + cc + 5] + rv1.y;
            ov1.z = smf[rr*SF + cc + 6] + rv1.z;
            ov1.w = smf[rr*SF + cc + 7] + rv1.w;
            *(float4*)&C[gro]     = ov0;
            *(float4*)&C[gro + 4] = ov1;
        }
    }
}

extern "C" void kernel_launch(void* const* d_in, const int* in_sizes, int n_in,
                              void* d_out, int out_size, void* d_ws, size_t ws_size,
                              hipStream_t stream) {
    (void)in_sizes; (void)n_in; (void)out_size; (void)ws_size;
    const float* x     = (const float*)d_in[0];
    const float* gn_w  = (const float*)d_in[1];
    const float* gn_b  = (const float*)d_in[2];
    const float* qkv_w = (const float*)d_in[3];
    const float* qkv_b = (const float*)d_in[4];
    const float* out_w = (const float*)d_in[5];
    const float* out_b = (const float*)d_in[6];
    float* out = (float*)d_out;

    char* ws = (char*)d_ws;
    u16*  h_t   = (u16*)ws;  ws += (size_t)16*1024*512*2;    // h[b][n][c]
    u16*  qkv_t = (u16*)ws;  ws += (size_t)16*1024*1024*2;   // qk[b][n][0..1023]
    u16*  v2    = (u16*)ws;  ws += (size_t)512*16384*2;      // v[c][b*1024+n]
    u16*  S     = (u16*)ws;  ws += (size_t)16*1024*1024*2;   // S/P[b][n][m]
    u16*  O     = (u16*)ws;  ws += (size_t)16*1024*512*2;    // O[b][n][c]
    u16*  wq    = (u16*)ws;  ws += (size_t)1536*512*2;
    u16*  wo    = (u16*)ws;  ws += (size_t)512*512*2;

    f2bf_kernel<<<(1536*512 + 255)/256, 256, 0, stream>>>(qkv_w, wq, 1536*512);
    f2bf_kernel<<<(512*512 + 255)/256, 256, 0, stream>>>(out_w, wo, 512*512);
    gn_fused_kernel<<<512, 256, 0, stream>>>(x, gn_w, gn_b, h_t);

    // QKV: M=1536, Nn=16384, K=512; q,k -> qkv_t[bn][m] transposed; v -> v2[c][bn]
    gemm_bt_kernel<2><<<dim3(128, 12, 1), 256, 0, stream>>>(
        wq, h_t, qkv_t, v2, qkv_b, nullptr, 1.0f,
        512, 512, 1024, 0, 0, 0, 0, 512);

    // S = q k^T * scale : per batch M=Nn=1024, K=512
    gemm_bt_kernel<1><<<dim3(8, 8, 16), 256, 0, stream>>>(
        qkv_t, qkv_t + 512, S, nullptr, nullptr, nullptr, 0.044194173824159216f,
        1024, 1024, 1024,
        (long long)1024*1024, (long long)1024*1024, (long long)1024*1024, 0, 512);

    softmax_kernel<<<4096, 256, 0, stream>>>(S);

    // O = P @ V : M=1024(n), Nn=512(c), K=1024(m); Bt = v2 (ldb 16384, per-batch col offset)
    gemm_bt_kernel<1><<<dim3(4, 8, 16), 256, 0, stream>>>(
        S, v2, O, nullptr, nullptr, nullptr, 1.0f,
        1024, 16384, 512,
        (long long)1024*1024, 1024, (long long)1024*512, 0, 1024);

    // out = out_w @ O^T + out_b + x : M=512(co), Nn=1024(n), K=512(ci), fp32 + residual
    gemm_bt_kernel<0><<<dim3(8, 4, 16), 256, 0, stream>>>(
        wo, O, out, nullptr, out_b, x, 1.0f,
        512, 512, 1024,
        0, (long long)1024*512, (long long)512*1024, (long long)512*1024, 512);
}

// Round 4
// 234.144 us; speedup vs baseline: 1.3500x; 1.1472x over previous
//
#include <hip/hip_runtime.h>

typedef unsigned short u16;
typedef short short8 __attribute__((ext_vector_type(8)));
typedef float floatx4 __attribute__((ext_vector_type(4)));
typedef u16 u16x4 __attribute__((ext_vector_type(4)));
typedef u16 u16x8 __attribute__((ext_vector_type(8)));

#define DEVI __device__ __forceinline__

DEVI u16 f2bf(float x) {
    union { float f; unsigned u; } c; c.f = x;
    unsigned u = c.u;
    u += 0x7fffu + ((u >> 16) & 1u);   // RNE
    return (u16)(u >> 16);
}
DEVI float bf2f(u16 h) {
    union { unsigned u; float f; } c; c.u = ((unsigned)h) << 16;
    return c.f;
}

DEVI void gload_lds16(const void* g, void* l) {
    auto gp = (const __attribute__((address_space(1))) unsigned*)(unsigned long long)g;
    auto lp = (__attribute__((address_space(3))) unsigned*)(unsigned)(unsigned long long)l;
    __builtin_amdgcn_global_load_lds(gp, lp, 16, 0, 0);
}

// ---------------- fused GroupNorm: stats + apply + transpose ----------------
__global__ __launch_bounds__(256) void gn_fused_kernel(const float* __restrict__ x,
                                                       const float* __restrict__ w,
                                                       const float* __restrict__ bb,
                                                       u16* __restrict__ h) {
    const int bg = blockIdx.x;           // b*32+g
    const int b = bg >> 5, g = bg & 31;
    const float* xg = x + (long long)bg * 16384;
    const float4* p4 = (const float4*)xg;
    float s = 0.f, s2 = 0.f;
    #pragma unroll
    for (int i = 0; i < 16; i++) {
        float4 v = p4[threadIdx.x + i * 256];
        s  += v.x + v.y + v.z + v.w;
        s2 += v.x*v.x + v.y*v.y + v.z*v.z + v.w*v.w;
    }
    #pragma unroll
    for (int m = 1; m < 64; m <<= 1) { s += __shfl_xor(s, m, 64); s2 += __shfl_xor(s2, m, 64); }
    __shared__ float rs[4], rq[4];
    if ((threadIdx.x & 63) == 0) { rs[threadIdx.x >> 6] = s; rq[threadIdx.x >> 6] = s2; }
    __syncthreads();
    float mean = (rs[0] + rs[1] + rs[2] + rs[3]) * (1.f / 16384.f);
    float var  = (rq[0] + rq[1] + rq[2] + rq[3]) * (1.f / 16384.f) - mean * mean;
    float rstd = rsqrtf(var + 1e-5f);

    float sc[16], sh[16];
    #pragma unroll
    for (int cc = 0; cc < 16; cc++) {
        int c = g * 16 + cc;
        sc[cc] = w[c] * rstd;
        sh[cc] = bb[c] - mean * sc[cc];
    }
    const int n0 = threadIdx.x * 4;
    u16x8 o[4][2];
    #pragma unroll
    for (int cc = 0; cc < 16; cc++) {
        float4 xv = *(const float4*)&xg[cc * 1024 + n0];
        o[0][cc >> 3][cc & 7] = f2bf(xv.x * sc[cc] + sh[cc]);
        o[1][cc >> 3][cc & 7] = f2bf(xv.y * sc[cc] + sh[cc]);
        o[2][cc >> 3][cc & 7] = f2bf(xv.z * sc[cc] + sh[cc]);
        o[3][cc >> 3][cc & 7] = f2bf(xv.w * sc[cc] + sh[cc]);
    }
    u16* hb = h + ((long long)b * 1024 + n0) * 512 + g * 16;
    #pragma unroll
    for (int k = 0; k < 4; k++) {
        *(u16x8*)&hb[(long long)k * 512]     = o[k][0];
        *(u16x8*)&hb[(long long)k * 512 + 8] = o[k][1];
    }
}

__global__ __launch_bounds__(256) void f2bf_kernel(const float* __restrict__ in,
                                                   u16* __restrict__ out, int n) {
    int i = blockIdx.x * 256 + threadIdx.x;
    if (i < n) out[i] = f2bf(in[i]);
}

// ---------------- softmax: one wave per row of 1024 ----------------
__global__ __launch_bounds__(256) void softmax_kernel(u16* __restrict__ P) {
    const int wave = threadIdx.x >> 6, lane = threadIdx.x & 63;
    const long long row = (long long)blockIdx.x * 4 + wave;
    u16* p = P + row * 1024 + lane * 16;
    u16x8 a = *(u16x8*)p;
    u16x8 b = *(u16x8*)(p + 8);
    float v[16];
    #pragma unroll
    for (int k = 0; k < 8; k++) { v[k] = bf2f(a[k]); v[8+k] = bf2f(b[k]); }
    float mx = v[0];
    #pragma unroll
    for (int k = 1; k < 16; k++) mx = fmaxf(mx, v[k]);
    #pragma unroll
    for (int m = 1; m < 64; m <<= 1) mx = fmaxf(mx, __shfl_xor(mx, m, 64));
    float s = 0.f;
    #pragma unroll
    for (int k = 0; k < 16; k++) { v[k] = __expf(v[k] - mx); s += v[k]; }
    #pragma unroll
    for (int m = 1; m < 64; m <<= 1) s += __shfl_xor(s, m, 64);
    float inv = 1.f / s;
    #pragma unroll
    for (int k = 0; k < 8; k++) { a[k] = f2bf(v[k]*inv); b[k] = f2bf(v[8+k]*inv); }
    *(u16x8*)p = a;
    *(u16x8*)(p + 8) = b;
}

// ---------------- TN GEMM, 128x128 tile, BK=64 (two packed BK=32 sub-tiles) ----------------
// MODE 0: fp32 out + bias + residual ([m][n])
// MODE 1: bf16 out, scaled ([m][n])
// MODE 2: QKV split: m0<1024 -> transposed bf16 C0[n][m] (+bias); else bf16 C1[(m-1024)][n] ld 16384 (+bias)
template <int MODE>
__global__ __launch_bounds__(256, 3)
void gemm_bt_kernel(const u16* __restrict__ A, const u16* __restrict__ Bt,
                    void* __restrict__ C0, void* __restrict__ C1,
                    const float* __restrict__ bias, const float* __restrict__ res,
                    float scale, int lda, int ldb, int ldc,
                    long long sA, long long sB, long long sC, long long sR, int K) {
    const int t    = threadIdx.x;
    const int lane = t & 63;
    const int wave = t >> 6;
    const int m0   = blockIdx.y * 128;
    const int n0   = blockIdx.x * 128;
    const int z    = blockIdx.z;
    A  += (long long)z * sA;
    Bt += (long long)z * sB;

    __shared__ __align__(16) u16 smem[16384];   // 32 KB: A[2][128][32] | B[2][128][32]
    u16* As = smem;
    u16* Bs = smem + 8192;

    const int wm = wave >> 1, wn = wave & 1;
    const int quad = lane >> 4, lrow = lane & 15;

    floatx4 acc[4][4];
    #pragma unroll
    for (int i = 0; i < 4; i++)
        #pragma unroll
        for (int j = 0; j < 4; j++)
            #pragma unroll
            for (int r = 0; r < 4; r++) acc[i][j][r] = 0.f;

    const int rowA = t >> 2;
    const int kch  = (t & 3) * 8;
    const u16* Ag = A  + (long long)(m0 + rowA) * lda + kch;
    const u16* Bg = Bt + (long long)(n0 + rowA) * ldb + kch;
    u16* Al = &As[t * 8];
    u16* Bl = &Bs[t * 8];
    const long long a64 = (long long)64 * lda;
    const long long b64 = (long long)64 * ldb;

    for (int k0 = 0; k0 < K; k0 += 64) {
        gload_lds16(Ag + k0,            Al);
        gload_lds16(Ag + k0 + a64,      Al + 2048);
        gload_lds16(Ag + k0 + 32,       Al + 4096);
        gload_lds16(Ag + k0 + 32 + a64, Al + 6144);
        gload_lds16(Bg + k0,            Bl);
        gload_lds16(Bg + k0 + b64,      Bl + 2048);
        gload_lds16(Bg + k0 + 32,       Bl + 4096);
        gload_lds16(Bg + k0 + 32 + b64, Bl + 6144);
        __syncthreads();
        #pragma unroll
        for (int kk = 0; kk < 2; kk++) {
            short8 af[4], bfr[4];
            #pragma unroll
            for (int i = 0; i < 4; i++)
                af[i] = *(const short8*)&As[kk*4096 + (wm*64 + i*16 + lrow)*32 + quad*8];
            #pragma unroll
            for (int j = 0; j < 4; j++)
                bfr[j] = *(const short8*)&Bs[kk*4096 + (wn*64 + j*16 + lrow)*32 + quad*8];
            #pragma unroll
            for (int i = 0; i < 4; i++)
                #pragma unroll
                for (int j = 0; j < 4; j++)
                    acc[i][j] = __builtin_amdgcn_mfma_f32_16x16x32_bf16(af[i], bfr[j], acc[i][j], 0, 0, 0);
        }
        __syncthreads();
    }
    // smem free from here

    const int ST = 136;  // u16 row stride (272 B = 17*16)

    if (MODE == 1 || (MODE == 2 && m0 >= 1024)) {
        #pragma unroll
        for (int p = 0; p < 4; p++) {
            if (p) __syncthreads();
            if (wm == (p >> 1)) {
                #pragma unroll
                for (int ii = 0; ii < 2; ii++) {
                    const int i = (p & 1) * 2 + ii;
                    const int row = ii * 16 + quad * 4;
                    #pragma unroll
                    for (int j = 0; j < 4; j++) {
                        const int cB = wn * 64 + j * 16 + lrow;
                        #pragma unroll
                        for (int r = 0; r < 4; r++) {
                            float v = acc[i][j][r] * (MODE == 1 ? scale : 1.0f);
                            if (MODE == 2) v += bias[m0 + p * 32 + row + r];
                            smem[(row + r) * ST + cB] = f2bf(v);
                        }
                    }
                }
            }
            __syncthreads();
            const int rr = t >> 3, cc = (t & 7) * 16;
            u16x8 a0 = *(u16x8*)&smem[rr * ST + cc];
            u16x8 a1 = *(u16x8*)&smem[rr * ST + cc + 8];
            u16* Cp;
            if (MODE == 1)
                Cp = (u16*)C0 + (long long)z * sC + (long long)(m0 + p * 32 + rr) * ldc + n0 + cc;
            else
                Cp = (u16*)C1 + (long long)(m0 - 1024 + p * 32 + rr) * 16384 + n0 + cc;
            *(u16x8*)Cp = a0;
            *(u16x8*)(Cp + 8) = a1;
        }
    } else if (MODE == 2) {
        #pragma unroll
        for (int p = 0; p < 4; p++) {
            if (p) __syncthreads();
            if (wn == (p >> 1)) {
                #pragma unroll
                for (int jj = 0; jj < 2; jj++) {
                    const int j = (p & 1) * 2 + jj;
                    const int row = jj * 16 + lrow;
                    #pragma unroll
                    for (int i = 0; i < 4; i++) {
                        const int mmL = wm * 64 + i * 16 + quad * 4;
                        u16x4 pk;
                        #pragma unroll
                        for (int r = 0; r < 4; r++)
                            pk[r] = f2bf(acc[i][j][r] + bias[m0 + mmL + r]);
                        *(u16x4*)&smem[row * ST + mmL] = pk;
                    }
                }
            }
            __syncthreads();
            const int rr = t >> 3, cc = (t & 7) * 16;
            u16x8 a0 = *(u16x8*)&smem[rr * ST + cc];
            u16x8 a1 = *(u16x8*)&smem[rr * ST + cc + 8];
            u16* Cp = (u16*)C0 + (long long)(n0 + p * 32 + rr) * 1024 + m0 + cc;
            *(u16x8*)Cp = a0;
            *(u16x8*)(Cp + 8) = a1;
        }
    } else {
        float* smf = (float*)smem;
        const int SF = 132;
        float* C = (float*)C0 + (long long)z * sC;
        const float* rz = res + (long long)z * sR;
        #pragma unroll
        for (int p = 0; p < 8; p++) {
            if (p) __syncthreads();
            if (wm == (p >> 2)) {
                const int i = p & 3;
                #pragma unroll
                for (int j = 0; j < 4; j++) {
                    const int cB = wn * 64 + j * 16 + lrow;
                    #pragma unroll
                    for (int r = 0; r < 4; r++)
                        smf[(quad * 4 + r) * SF + cB] =
                            acc[i][j][r] + bias[m0 + p * 16 + quad * 4 + r];
                }
            }
            __syncthreads();
            const int rr = t >> 4, cc = (t & 15) * 8;
            const long long gro = (long long)(m0 + p * 16 + rr) * ldc + n0 + cc;
            float4 rv0 = *(const float4*)&rz[gro];
            float4 rv1 = *(const float4*)&rz[gro + 4];
            float4 ov0, ov1;
            ov0.x = smf[rr*SF + cc + 0] + rv0.x;
            ov0.y = smf[rr*SF + cc + 1] + rv0.y;
            ov0.z = smf[rr*SF + cc + 2] + rv0.z;
            ov0.w = smf[rr*SF + cc + 3] + rv0.w;
            ov1.x = smf[rr*SF + cc + 4] + rv1.x;
            ov1.y = smf[rr*SF + cc + 5] + rv1.y;
            ov1.z = smf[rr*SF + cc + 6] + rv1.z;
            ov1.w = smf[rr*SF + cc + 7] + rv1.w;
            *(float4*)&C[gro]     = ov0;
            *(float4*)&C[gro + 4] = ov1;
        }
    }
}

extern "C" void kernel_launch(void* const* d_in, const int* in_sizes, int n_in,
                              void* d_out, int out_size, void* d_ws, size_t ws_size,
                              hipStream_t stream) {
    (void)in_sizes; (void)n_in; (void)out_size; (void)ws_size;
    const float* x     = (const float*)d_in[0];
    const float* gn_w  = (const float*)d_in[1];
    const float* gn_b  = (const float*)d_in[2];
    const float* qkv_w = (const float*)d_in[3];
    const float* qkv_b = (const float*)d_in[4];
    const float* out_w = (const float*)d_in[5];
    const float* out_b = (const float*)d_in[6];
    float* out = (float*)d_out;

    char* ws = (char*)d_ws;
    u16*  h_t   = (u16*)ws;  ws += (size_t)16*1024*512*2;    // h[b][n][c]
    u16*  qkv_t = (u16*)ws;  ws += (size_t)16*1024*1024*2;   // qk[b][n][0..1023]
    u16*  v2    = (u16*)ws;  ws += (size_t)512*16384*2;      // v[c][b*1024+n]
    u16*  S     = (u16*)ws;  ws += (size_t)16*1024*1024*2;   // S/P[b][n][m]
    u16*  O     = (u16*)ws;  ws += (size_t)16*1024*512*2;    // O[b][n][c]
    u16*  wq    = (u16*)ws;  ws += (size_t)1536*512*2;
    u16*  wo    = (u16*)ws;  ws += (size_t)512*512*2;

    f2bf_kernel<<<(1536*512 + 255)/256, 256, 0, stream>>>(qkv_w, wq, 1536*512);
    f2bf_kernel<<<(512*512 + 255)/256, 256, 0, stream>>>(out_w, wo, 512*512);
    gn_fused_kernel<<<512, 256, 0, stream>>>(x, gn_w, gn_b, h_t);

    // QKV: M=1536, Nn=16384, K=512; q,k -> qkv_t[bn][m] transposed; v -> v2[c][bn]
    gemm_bt_kernel<2><<<dim3(128, 12, 1), 256, 0, stream>>>(
        wq, h_t, qkv_t, v2, qkv_b, nullptr, 1.0f,
        512, 512, 1024, 0, 0, 0, 0, 512);

    // S = q k^T * scale : per batch M=Nn=1024, K=512
    gemm_bt_kernel<1><<<dim3(8, 8, 16), 256, 0, stream>>>(
        qkv_t, qkv_t + 512, S, nullptr, nullptr, nullptr, 0.044194173824159216f,
        1024, 1024, 1024,
        (long long)1024*1024, (long long)1024*1024, (long long)1024*1024, 0, 512);

    softmax_kernel<<<4096, 256, 0, stream>>>(S);

    // O = P @ V : M=1024(n), Nn=512(c), K=1024(m); Bt = v2 (ldb 16384, per-batch col offset)
    gemm_bt_kernel<1><<<dim3(4, 8, 16), 256, 0, stream>>>(
        S, v2, O, nullptr, nullptr, nullptr, 1.0f,
        1024, 16384, 512,
        (long long)1024*1024, 1024, (long long)1024*512, 0, 1024);

    // out = out_w @ O^T + out_b + x : M=512(co), Nn=1024(n), K=512(ci), fp32 + residual
    gemm_bt_kernel<0><<<dim3(8, 4, 16), 256, 0, stream>>>(
        wo, O, out, nullptr, out_b, x, 1.0f,
        512, 512, 1024,
        0, (long long)1024*512, (long long)512*1024, (long long)512*1024, 512);
}

// Round 5
// 231.201 us; speedup vs baseline: 1.3671x; 1.0127x over previous
//
#include <hip/hip_runtime.h>

typedef unsigned short u16;
typedef short short8 __attribute__((ext_vector_type(8)));
typedef float floatx4 __attribute__((ext_vector_type(4)));
typedef u16 u16x4 __attribute__((ext_vector_type(4)));
typedef u16 u16x8 __attribute__((ext_vector_type(8)));

#define DEVI __device__ __forceinline__

DEVI u16 f2bf(float x) {
    union { float f; unsigned u; } c; c.f = x;
    unsigned u = c.u;
    u += 0x7fffu + ((u >> 16) & 1u);   // RNE
    return (u16)(u >> 16);
}
DEVI float bf2f(u16 h) {
    union { unsigned u; float f; } c; c.u = ((unsigned)h) << 16;
    return c.f;
}

DEVI void gload_lds16(const void* g, void* l) {
    auto gp = (const __attribute__((address_space(1))) unsigned*)(unsigned long long)g;
    auto lp = (__attribute__((address_space(3))) unsigned*)(unsigned)(unsigned long long)l;
    __builtin_amdgcn_global_load_lds(gp, lp, 16, 0, 0);
}

// ---------------- fused GroupNorm: single global read, stats + apply in regs ----------------
// one block per (b,g). thread t owns n-cols [t*4, t*4+4) for all 16 channels of the group.
__global__ __launch_bounds__(256) void gn_fused_kernel(const float* __restrict__ x,
                                                       const float* __restrict__ w,
                                                       const float* __restrict__ bb,
                                                       u16* __restrict__ h) {
    const int bg = blockIdx.x;           // b*32+g
    const int b = bg >> 5, g = bg & 31;
    const float* xg = x + (long long)bg * 16384;
    const int n0 = threadIdx.x * 4;

    float4 xv[16];
    float s = 0.f, s2 = 0.f;
    #pragma unroll
    for (int cc = 0; cc < 16; cc++) {
        xv[cc] = *(const float4*)&xg[cc * 1024 + n0];
        s  += xv[cc].x + xv[cc].y + xv[cc].z + xv[cc].w;
        s2 += xv[cc].x*xv[cc].x + xv[cc].y*xv[cc].y + xv[cc].z*xv[cc].z + xv[cc].w*xv[cc].w;
    }
    #pragma unroll
    for (int m = 1; m < 64; m <<= 1) { s += __shfl_xor(s, m, 64); s2 += __shfl_xor(s2, m, 64); }
    __shared__ float rs[4], rq[4];
    if ((threadIdx.x & 63) == 0) { rs[threadIdx.x >> 6] = s; rq[threadIdx.x >> 6] = s2; }
    __syncthreads();
    float mean = (rs[0] + rs[1] + rs[2] + rs[3]) * (1.f / 16384.f);
    float var  = (rq[0] + rq[1] + rq[2] + rq[3]) * (1.f / 16384.f) - mean * mean;
    float rstd = rsqrtf(var + 1e-5f);

    u16x8 o[4][2];
    #pragma unroll
    for (int cc = 0; cc < 16; cc++) {
        int c = g * 16 + cc;
        float sc = w[c] * rstd;
        float sh = bb[c] - mean * sc;
        o[0][cc >> 3][cc & 7] = f2bf(xv[cc].x * sc + sh);
        o[1][cc >> 3][cc & 7] = f2bf(xv[cc].y * sc + sh);
        o[2][cc >> 3][cc & 7] = f2bf(xv[cc].z * sc + sh);
        o[3][cc >> 3][cc & 7] = f2bf(xv[cc].w * sc + sh);
    }
    u16* hb = h + ((long long)b * 1024 + n0) * 512 + g * 16;
    #pragma unroll
    for (int k = 0; k < 4; k++) {
        *(u16x8*)&hb[(long long)k * 512]     = o[k][0];
        *(u16x8*)&hb[(long long)k * 512 + 8] = o[k][1];
    }
}

// ---------------- both weight conversions in one launch, float4 -> u16x4 ----------------
__global__ __launch_bounds__(256) void wconv_kernel(const float* __restrict__ w1, u16* __restrict__ o1,
                                                    const float* __restrict__ w2, u16* __restrict__ o2) {
    int i = blockIdx.x * 256 + threadIdx.x;   // of 262144 float4 slots
    const float* src; u16* dst; int j;
    if (i < 196608) { src = w1; dst = o1; j = i; }
    else            { src = w2; dst = o2; j = i - 196608; }
    float4 v = *(const float4*)&src[j * 4];
    u16x4 p; p[0] = f2bf(v.x); p[1] = f2bf(v.y); p[2] = f2bf(v.z); p[3] = f2bf(v.w);
    *(u16x4*)&dst[j * 4] = p;
}

// ---------------- softmax: one wave per row of 1024 ----------------
__global__ __launch_bounds__(256) void softmax_kernel(u16* __restrict__ P) {
    const int wave = threadIdx.x >> 6, lane = threadIdx.x & 63;
    const long long row = (long long)blockIdx.x * 4 + wave;
    u16* p = P + row * 1024 + lane * 16;
    u16x8 a = *(u16x8*)p;
    u16x8 b = *(u16x8*)(p + 8);
    float v[16];
    #pragma unroll
    for (int k = 0; k < 8; k++) { v[k] = bf2f(a[k]); v[8+k] = bf2f(b[k]); }
    float mx = v[0];
    #pragma unroll
    for (int k = 1; k < 16; k++) mx = fmaxf(mx, v[k]);
    #pragma unroll
    for (int m = 1; m < 64; m <<= 1) mx = fmaxf(mx, __shfl_xor(mx, m, 64));
    float s = 0.f;
    #pragma unroll
    for (int k = 0; k < 16; k++) { v[k] = __expf(v[k] - mx); s += v[k]; }
    #pragma unroll
    for (int m = 1; m < 64; m <<= 1) s += __shfl_xor(s, m, 64);
    float inv = 1.f / s;
    #pragma unroll
    for (int k = 0; k < 8; k++) { a[k] = f2bf(v[k]*inv); b[k] = f2bf(v[8+k]*inv); }
    *(u16x8*)p = a;
    *(u16x8*)(p + 8) = b;
}

// ---------------- TN GEMM, 128x128 tile, BK=64 ----------------
// MODE 0: fp32 out + bias[m] + residual ([m][n])
// MODE 1: bf16 out, scaled ([m][n])
// MODE 2: bf16 transposed out C0[n][m] + bias[m]
template <int MODE>
__global__ __launch_bounds__(256, 3)
void gemm_bt_kernel(const u16* __restrict__ A, const u16* __restrict__ Bt,
                    void* __restrict__ C0,
                    const float* __restrict__ bias, const float* __restrict__ res,
                    float scale, int lda, int ldb, int ldc,
                    long long sA, long long sB, long long sC, long long sR, int K) {
    const int t    = threadIdx.x;
    const int lane = t & 63;
    const int wave = t >> 6;
    const int m0   = blockIdx.y * 128;
    const int n0   = blockIdx.x * 128;
    const int z    = blockIdx.z;
    A  += (long long)z * sA;
    Bt += (long long)z * sB;

    __shared__ __align__(16) u16 smem[16384];   // 32 KB: A[2][128][32] | B[2][128][32]
    u16* As = smem;
    u16* Bs = smem + 8192;

    const int wm = wave >> 1, wn = wave & 1;
    const int quad = lane >> 4, lrow = lane & 15;

    floatx4 acc[4][4];
    #pragma unroll
    for (int i = 0; i < 4; i++)
        #pragma unroll
        for (int j = 0; j < 4; j++)
            #pragma unroll
            for (int r = 0; r < 4; r++) acc[i][j][r] = 0.f;

    const int rowA = t >> 2;
    const int kch  = (t & 3) * 8;
    const u16* Ag = A  + (long long)(m0 + rowA) * lda + kch;
    const u16* Bg = Bt + (long long)(n0 + rowA) * ldb + kch;
    u16* Al = &As[t * 8];
    u16* Bl = &Bs[t * 8];
    const long long a64 = (long long)64 * lda;
    const long long b64 = (long long)64 * ldb;

    for (int k0 = 0; k0 < K; k0 += 64) {
        gload_lds16(Ag + k0,            Al);
        gload_lds16(Ag + k0 + a64,      Al + 2048);
        gload_lds16(Ag + k0 + 32,       Al + 4096);
        gload_lds16(Ag + k0 + 32 + a64, Al + 6144);
        gload_lds16(Bg + k0,            Bl);
        gload_lds16(Bg + k0 + b64,      Bl + 2048);
        gload_lds16(Bg + k0 + 32,       Bl + 4096);
        gload_lds16(Bg + k0 + 32 + b64, Bl + 6144);
        __syncthreads();
        #pragma unroll
        for (int kk = 0; kk < 2; kk++) {
            short8 af[4], bfr[4];
            #pragma unroll
            for (int i = 0; i < 4; i++)
                af[i] = *(const short8*)&As[kk*4096 + (wm*64 + i*16 + lrow)*32 + quad*8];
            #pragma unroll
            for (int j = 0; j < 4; j++)
                bfr[j] = *(const short8*)&Bs[kk*4096 + (wn*64 + j*16 + lrow)*32 + quad*8];
            #pragma unroll
            for (int i = 0; i < 4; i++)
                #pragma unroll
                for (int j = 0; j < 4; j++)
                    acc[i][j] = __builtin_amdgcn_mfma_f32_16x16x32_bf16(af[i], bfr[j], acc[i][j], 0, 0, 0);
        }
        __syncthreads();
    }
    // smem free from here

    const int ST = 136;  // u16 row stride (272 B = 17*16)

    if (MODE == 1) {
        #pragma unroll
        for (int p = 0; p < 4; p++) {
            if (p) __syncthreads();
            if (wm == (p >> 1)) {
                #pragma unroll
                for (int ii = 0; ii < 2; ii++) {
                    const int i = (p & 1) * 2 + ii;
                    const int row = ii * 16 + quad * 4;
                    #pragma unroll
                    for (int j = 0; j < 4; j++) {
                        const int cB = wn * 64 + j * 16 + lrow;
                        #pragma unroll
                        for (int r = 0; r < 4; r++)
                            smem[(row + r) * ST + cB] = f2bf(acc[i][j][r] * scale);
                    }
                }
            }
            __syncthreads();
            const int rr = t >> 3, cc = (t & 7) * 16;
            u16x8 a0 = *(u16x8*)&smem[rr * ST + cc];
            u16x8 a1 = *(u16x8*)&smem[rr * ST + cc + 8];
            u16* Cp = (u16*)C0 + (long long)z * sC + (long long)(m0 + p * 32 + rr) * ldc + n0 + cc;
            *(u16x8*)Cp = a0;
            *(u16x8*)(Cp + 8) = a1;
        }
    } else if (MODE == 2) {
        // transposed bf16: C0[n][m] with ldc, 4 chunks of 32 n-rows
        #pragma unroll
        for (int p = 0; p < 4; p++) {
            if (p) __syncthreads();
            if (wn == (p >> 1)) {
                #pragma unroll
                for (int jj = 0; jj < 2; jj++) {
                    const int j = (p & 1) * 2 + jj;
                    const int row = jj * 16 + lrow;
                    #pragma unroll
                    for (int i = 0; i < 4; i++) {
                        const int mmL = wm * 64 + i * 16 + quad * 4;
                        u16x4 pk;
                        #pragma unroll
                        for (int r = 0; r < 4; r++)
                            pk[r] = f2bf(acc[i][j][r] + bias[m0 + mmL + r]);
                        *(u16x4*)&smem[row * ST + mmL] = pk;
                    }
                }
            }
            __syncthreads();
            const int rr = t >> 3, cc = (t & 7) * 16;
            u16x8 a0 = *(u16x8*)&smem[rr * ST + cc];
            u16x8 a1 = *(u16x8*)&smem[rr * ST + cc + 8];
            u16* Cp = (u16*)C0 + (long long)(n0 + p * 32 + rr) * ldc + m0 + cc;
            *(u16x8*)Cp = a0;
            *(u16x8*)(Cp + 8) = a1;
        }
    } else {
        // MODE 0: fp32 + bias + residual, 8 chunks of 16 rows
        float* smf = (float*)smem;
        const int SF = 132;
        float* C = (float*)C0 + (long long)z * sC;
        const float* rz = res + (long long)z * sR;
        #pragma unroll
        for (int p = 0; p < 8; p++) {
            if (p) __syncthreads();
            if (wm == (p >> 2)) {
                const int i = p & 3;
                #pragma unroll
                for (int j = 0; j < 4; j++) {
                    const int cB = wn * 64 + j * 16 + lrow;
                    #pragma unroll
                    for (int r = 0; r < 4; r++)
                        smf[(quad * 4 + r) * SF + cB] =
                            acc[i][j][r] + bias[m0 + p * 16 + quad * 4 + r];
                }
            }
            __syncthreads();
            const int rr = t >> 4, cc = (t & 15) * 8;
            const long long gro = (long long)(m0 + p * 16 + rr) * ldc + n0 + cc;
            float4 rv0 = *(const float4*)&rz[gro];
            float4 rv1 = *(const float4*)&rz[gro + 4];
            float4 ov0, ov1;
            ov0.x = smf[rr*SF + cc + 0] + rv0.x;
            ov0.y = smf[rr*SF + cc + 1] + rv0.y;
            ov0.z = smf[rr*SF + cc + 2] + rv0.z;
            ov0.w = smf[rr*SF + cc + 3] + rv0.w;
            ov1.x = smf[rr*SF + cc + 4] + rv1.x;
            ov1.y = smf[rr*SF + cc + 5] + rv1.y;
            ov1.z = smf[rr*SF + cc + 6] + rv1.z;
            ov1.w = smf[rr*SF + cc + 7] + rv1.w;
            *(float4*)&C[gro]     = ov0;
            *(float4*)&C[gro + 4] = ov1;
        }
    }
}

extern "C" void kernel_launch(void* const* d_in, const int* in_sizes, int n_in,
                              void* d_out, int out_size, void* d_ws, size_t ws_size,
                              hipStream_t stream) {
    (void)in_sizes; (void)n_in; (void)out_size; (void)ws_size;
    const float* x     = (const float*)d_in[0];
    const float* gn_w  = (const float*)d_in[1];
    const float* gn_b  = (const float*)d_in[2];
    const float* qkv_w = (const float*)d_in[3];
    const float* qkv_b = (const float*)d_in[4];
    const float* out_w = (const float*)d_in[5];
    const float* out_b = (const float*)d_in[6];
    float* out = (float*)d_out;

    char* ws = (char*)d_ws;
    u16*  h_t   = (u16*)ws;  ws += (size_t)16*1024*512*2;    // 16 MB h[b][n][c]
    u16*  qkv_t = (u16*)ws;  ws += (size_t)16*1024*1536*2;   // 48 MB qkv[b*n][1536] (q|k|v)
    u16*  vprm  = (u16*)ws;  ws += (size_t)512*16384*2;      // 16 MB V' = (V Wo^T)^T : [c_out][b*1024+n]
    u16*  S     = (u16*)ws;  ws += (size_t)16*1024*1024*2;   // 32 MB S/P[b][n][m]
    u16*  wq    = (u16*)ws;  ws += (size_t)1536*512*2;
    u16*  wo    = (u16*)ws;  ws += (size_t)512*512*2;

    wconv_kernel<<<1024, 256, 0, stream>>>(qkv_w, wq, out_w, wo);
    gn_fused_kernel<<<512, 256, 0, stream>>>(x, gn_w, gn_b, h_t);

    // QKV: M=1536, Nn=16384, K=512 ; all transposed -> qkv_t[bn][1536] + bias
    gemm_bt_kernel<2><<<dim3(128, 12, 1), 256, 0, stream>>>(
        wq, h_t, qkv_t, qkv_b, nullptr, 1.0f,
        512, 512, 1536, 0, 0, 0, 0, 512);

    // V' = Wo @ V^T : M=512(c_out), Nn=16384(bn), K=512(c_in); Bt = v rows of qkv_t
    gemm_bt_kernel<1><<<dim3(128, 4, 1), 256, 0, stream>>>(
        wo, qkv_t + 1024, vprm, nullptr, nullptr, 1.0f,
        512, 1536, 16384, 0, 0, 0, 0, 512);

    // S = q k^T * scale : per batch M=Nn=1024, K=512
    gemm_bt_kernel<1><<<dim3(8, 8, 16), 256, 0, stream>>>(
        qkv_t, qkv_t + 512, S, nullptr, nullptr, 0.044194173824159216f,
        1536, 1536, 1024,
        (long long)1024*1536, (long long)1024*1536, (long long)1024*1024, 0, 512);

    softmax_kernel<<<4096, 256, 0, stream>>>(S);

    // out = V'^T-weighted P + out_b + x : M=512(c_out), Nn=1024(n), K=1024(m tokens)
    // A = vprm (lda 16384, per-batch col offset 1024), Bt = P rows (ldb 1024)
    gemm_bt_kernel<0><<<dim3(8, 4, 16), 256, 0, stream>>>(
        vprm, S, out, out_b, x, 1.0f,
        16384, 1024, 1024,
        1024, (long long)1024*1024, (long long)512*1024, (long long)512*1024, 1024);
}

// Round 6
// 217.596 us; speedup vs baseline: 1.4526x; 1.0625x over previous
//
#include <hip/hip_runtime.h>

typedef unsigned short u16;
typedef short short8 __attribute__((ext_vector_type(8)));
typedef float floatx4 __attribute__((ext_vector_type(4)));
typedef u16 u16x4 __attribute__((ext_vector_type(4)));
typedef u16 u16x8 __attribute__((ext_vector_type(8)));

#define DEVI __device__ __forceinline__

DEVI u16 f2bf(float x) {
    union { float f; unsigned u; } c; c.f = x;
    unsigned u = c.u;
    u += 0x7fffu + ((u >> 16) & 1u);   // RNE
    return (u16)(u >> 16);
}
DEVI float bf2f(u16 h) {
    union { unsigned u; float f; } c; c.u = ((unsigned)h) << 16;
    return c.f;
}

DEVI void gload_lds16(const void* g, void* l) {
    auto gp = (const __attribute__((address_space(1))) unsigned*)(unsigned long long)g;
    auto lp = (__attribute__((address_space(3))) unsigned*)(unsigned)(unsigned long long)l;
    __builtin_amdgcn_global_load_lds(gp, lp, 16, 0, 0);
}

// ---------------- fused GroupNorm: single global read, stats + apply in regs ----------------
__global__ __launch_bounds__(256) void gn_fused_kernel(const float* __restrict__ x,
                                                       const float* __restrict__ w,
                                                       const float* __restrict__ bb,
                                                       u16* __restrict__ h) {
    const int bg = blockIdx.x;           // b*32+g
    const int b = bg >> 5, g = bg & 31;
    const float* xg = x + (long long)bg * 16384;
    const int n0 = threadIdx.x * 4;

    float4 xv[16];
    float s = 0.f, s2 = 0.f;
    #pragma unroll
    for (int cc = 0; cc < 16; cc++) {
        xv[cc] = *(const float4*)&xg[cc * 1024 + n0];
        s  += xv[cc].x + xv[cc].y + xv[cc].z + xv[cc].w;
        s2 += xv[cc].x*xv[cc].x + xv[cc].y*xv[cc].y + xv[cc].z*xv[cc].z + xv[cc].w*xv[cc].w;
    }
    #pragma unroll
    for (int m = 1; m < 64; m <<= 1) { s += __shfl_xor(s, m, 64); s2 += __shfl_xor(s2, m, 64); }
    __shared__ float rs[4], rq[4];
    if ((threadIdx.x & 63) == 0) { rs[threadIdx.x >> 6] = s; rq[threadIdx.x >> 6] = s2; }
    __syncthreads();
    float mean = (rs[0] + rs[1] + rs[2] + rs[3]) * (1.f / 16384.f);
    float var  = (rq[0] + rq[1] + rq[2] + rq[3]) * (1.f / 16384.f) - mean * mean;
    float rstd = rsqrtf(var + 1e-5f);

    u16x8 o[4][2];
    #pragma unroll
    for (int cc = 0; cc < 16; cc++) {
        int c = g * 16 + cc;
        float sc = w[c] * rstd;
        float sh = bb[c] - mean * sc;
        o[0][cc >> 3][cc & 7] = f2bf(xv[cc].x * sc + sh);
        o[1][cc >> 3][cc & 7] = f2bf(xv[cc].y * sc + sh);
        o[2][cc >> 3][cc & 7] = f2bf(xv[cc].z * sc + sh);
        o[3][cc >> 3][cc & 7] = f2bf(xv[cc].w * sc + sh);
    }
    u16* hb = h + ((long long)b * 1024 + n0) * 512 + g * 16;
    #pragma unroll
    for (int k = 0; k < 4; k++) {
        *(u16x8*)&hb[(long long)k * 512]     = o[k][0];
        *(u16x8*)&hb[(long long)k * 512 + 8] = o[k][1];
    }
}

// ---------------- both weight conversions in one launch ----------------
__global__ __launch_bounds__(256) void wconv_kernel(const float* __restrict__ w1, u16* __restrict__ o1,
                                                    const float* __restrict__ w2, u16* __restrict__ o2) {
    int i = blockIdx.x * 256 + threadIdx.x;   // of 262144 float4 slots
    const float* src; u16* dst; int j;
    if (i < 196608) { src = w1; dst = o1; j = i; }
    else            { src = w2; dst = o2; j = i - 196608; }
    float4 v = *(const float4*)&src[j * 4];
    u16x4 p; p[0] = f2bf(v.x); p[1] = f2bf(v.y); p[2] = f2bf(v.z); p[3] = f2bf(v.w);
    *(u16x4*)&dst[j * 4] = p;
}

// ---------------- softmax: one wave per row, XCD-affine (batch z -> XCD z&7) ----------------
__global__ __launch_bounds__(256) void softmax_kernel(u16* __restrict__ P) {
    const int lid  = blockIdx.x;            // 4096 blocks
    const int xcd  = lid & 7;
    const int slot = lid >> 3;              // 0..511
    const int j    = slot >> 8;             // 0..1
    const int w    = slot & 255;            // block-in-batch
    const int z    = xcd + 8 * j;
    const int wave = threadIdx.x >> 6, lane = threadIdx.x & 63;
    const long long row = (long long)z * 1024 + w * 4 + wave;
    u16* p = P + row * 1024 + lane * 16;
    u16x8 a = *(u16x8*)p;
    u16x8 b = *(u16x8*)(p + 8);
    float v[16];
    #pragma unroll
    for (int k = 0; k < 8; k++) { v[k] = bf2f(a[k]); v[8+k] = bf2f(b[k]); }
    float mx = v[0];
    #pragma unroll
    for (int k = 1; k < 16; k++) mx = fmaxf(mx, v[k]);
    #pragma unroll
    for (int m = 1; m < 64; m <<= 1) mx = fmaxf(mx, __shfl_xor(mx, m, 64));
    float s = 0.f;
    #pragma unroll
    for (int k = 0; k < 16; k++) { v[k] = __expf(v[k] - mx); s += v[k]; }
    #pragma unroll
    for (int m = 1; m < 64; m <<= 1) s += __shfl_xor(s, m, 64);
    float inv = 1.f / s;
    #pragma unroll
    for (int k = 0; k < 8; k++) { a[k] = f2bf(v[k]*inv); b[k] = f2bf(v[8+k]*inv); }
    *(u16x8*)p = a;
    *(u16x8*)(p + 8) = b;
}

// ---------------- TN GEMM, 128x128 tile, BK=64 ----------------
// MODE 0: fp32 out + bias[m] + residual ([m][n])
// MODE 1: bf16 out, scaled ([m][n])
// MODE 2: bf16 transposed out C0[n][m] + bias[m]
// NX>0: 1D launch of NX*NY*nz blocks, decoded so batch z runs on XCD z&7.
template <int MODE, int NX, int NY>
__global__ __launch_bounds__(256, 3)
void gemm_bt_kernel(const u16* __restrict__ A, const u16* __restrict__ Bt,
                    void* __restrict__ C0,
                    const float* __restrict__ bias, const float* __restrict__ res,
                    float scale, int lda, int ldb, int ldc,
                    long long sA, long long sB, long long sC, long long sR, int K) {
    int bx, by, bz;
    if (NX > 0) {
        const int lid  = blockIdx.x;
        const int xcd  = lid & 7;
        const int slot = lid >> 3;
        const int per  = NX * NY;
        const int j    = slot / per;
        const int w    = slot - j * per;
        bz = xcd + 8 * j;
        bx = w % NX;
        by = w / NX;
    } else {
        bx = blockIdx.x; by = blockIdx.y; bz = blockIdx.z;
    }
    const int t    = threadIdx.x;
    const int lane = t & 63;
    const int wave = t >> 6;
    const int m0   = by * 128;
    const int n0   = bx * 128;
    A  += (long long)bz * sA;
    Bt += (long long)bz * sB;

    __shared__ __align__(16) u16 smem[16384];   // 32 KB: A[2][128][32] | B[2][128][32]
    u16* As = smem;
    u16* Bs = smem + 8192;

    const int wm = wave >> 1, wn = wave & 1;
    const int quad = lane >> 4, lrow = lane & 15;

    floatx4 acc[4][4];
    #pragma unroll
    for (int i = 0; i < 4; i++)
        #pragma unroll
        for (int j = 0; j < 4; j++)
            #pragma unroll
            for (int r = 0; r < 4; r++) acc[i][j][r] = 0.f;

    const int rowA = t >> 2;
    const int kch  = (t & 3) * 8;
    const u16* Ag = A  + (long long)(m0 + rowA) * lda + kch;
    const u16* Bg = Bt + (long long)(n0 + rowA) * ldb + kch;
    u16* Al = &As[t * 8];
    u16* Bl = &Bs[t * 8];
    const long long a64 = (long long)64 * lda;
    const long long b64 = (long long)64 * ldb;

    for (int k0 = 0; k0 < K; k0 += 64) {
        gload_lds16(Ag + k0,            Al);
        gload_lds16(Ag + k0 + a64,      Al + 2048);
        gload_lds16(Ag + k0 + 32,       Al + 4096);
        gload_lds16(Ag + k0 + 32 + a64, Al + 6144);
        gload_lds16(Bg + k0,            Bl);
        gload_lds16(Bg + k0 + b64,      Bl + 2048);
        gload_lds16(Bg + k0 + 32,       Bl + 4096);
        gload_lds16(Bg + k0 + 32 + b64, Bl + 6144);
        __syncthreads();
        #pragma unroll
        for (int kk = 0; kk < 2; kk++) {
            short8 af[4], bfr[4];
            #pragma unroll
            for (int i = 0; i < 4; i++)
                af[i] = *(const short8*)&As[kk*4096 + (wm*64 + i*16 + lrow)*32 + quad*8];
            #pragma unroll
            for (int j = 0; j < 4; j++)
                bfr[j] = *(const short8*)&Bs[kk*4096 + (wn*64 + j*16 + lrow)*32 + quad*8];
            #pragma unroll
            for (int i = 0; i < 4; i++)
                #pragma unroll
                for (int j = 0; j < 4; j++)
                    acc[i][j] = __builtin_amdgcn_mfma_f32_16x16x32_bf16(af[i], bfr[j], acc[i][j], 0, 0, 0);
        }
        __syncthreads();
    }
    // smem free from here

    const int ST = 136;  // u16 row stride (272 B = 17*16)

    if (MODE == 1) {
        #pragma unroll
        for (int p = 0; p < 4; p++) {
            if (p) __syncthreads();
            if (wm == (p >> 1)) {
                #pragma unroll
                for (int ii = 0; ii < 2; ii++) {
                    const int i = (p & 1) * 2 + ii;
                    const int row = ii * 16 + quad * 4;
                    #pragma unroll
                    for (int j = 0; j < 4; j++) {
                        const int cB = wn * 64 + j * 16 + lrow;
                        #pragma unroll
                        for (int r = 0; r < 4; r++)
                            smem[(row + r) * ST + cB] = f2bf(acc[i][j][r] * scale);
                    }
                }
            }
            __syncthreads();
            const int rr = t >> 3, cc = (t & 7) * 16;
            u16x8 a0 = *(u16x8*)&smem[rr * ST + cc];
            u16x8 a1 = *(u16x8*)&smem[rr * ST + cc + 8];
            u16* Cp = (u16*)C0 + (long long)bz * sC + (long long)(m0 + p * 32 + rr) * ldc + n0 + cc;
            *(u16x8*)Cp = a0;
            *(u16x8*)(Cp + 8) = a1;
        }
    } else if (MODE == 2) {
        #pragma unroll
        for (int p = 0; p < 4; p++) {
            if (p) __syncthreads();
            if (wn == (p >> 1)) {
                #pragma unroll
                for (int jj = 0; jj < 2; jj++) {
                    const int j = (p & 1) * 2 + jj;
                    const int row = jj * 16 + lrow;
                    #pragma unroll
                    for (int i = 0; i < 4; i++) {
                        const int mmL = wm * 64 + i * 16 + quad * 4;
                        u16x4 pk;
                        #pragma unroll
                        for (int r = 0; r < 4; r++)
                            pk[r] = f2bf(acc[i][j][r] + bias[m0 + mmL + r]);
                        *(u16x4*)&smem[row * ST + mmL] = pk;
                    }
                }
            }
            __syncthreads();
            const int rr = t >> 3, cc = (t & 7) * 16;
            u16x8 a0 = *(u16x8*)&smem[rr * ST + cc];
            u16x8 a1 = *(u16x8*)&smem[rr * ST + cc + 8];
            u16* Cp = (u16*)C0 + (long long)(n0 + p * 32 + rr) * ldc + m0 + cc;
            *(u16x8*)Cp = a0;
            *(u16x8*)(Cp + 8) = a1;
        }
    } else {
        float* smf = (float*)smem;
        const int SF = 132;
        float* C = (float*)C0 + (long long)bz * sC;
        const float* rz = res + (long long)bz * sR;
        #pragma unroll
        for (int p = 0; p < 8; p++) {
            if (p) __syncthreads();
            if (wm == (p >> 2)) {
                const int i = p & 3;
                #pragma unroll
                for (int j = 0; j < 4; j++) {
                    const int cB = wn * 64 + j * 16 + lrow;
                    #pragma unroll
                    for (int r = 0; r < 4; r++)
                        smf[(quad * 4 + r) * SF + cB] =
                            acc[i][j][r] + bias[m0 + p * 16 + quad * 4 + r];
                }
            }
            __syncthreads();
            const int rr = t >> 4, cc = (t & 15) * 8;
            const long long gro = (long long)(m0 + p * 16 + rr) * ldc + n0 + cc;
            float4 rv0 = *(const float4*)&rz[gro];
            float4 rv1 = *(const float4*)&rz[gro + 4];
            float4 ov0, ov1;
            ov0.x = smf[rr*SF + cc + 0] + rv0.x;
            ov0.y = smf[rr*SF + cc + 1] + rv0.y;
            ov0.z = smf[rr*SF + cc + 2] + rv0.z;
            ov0.w = smf[rr*SF + cc + 3] + rv0.w;
            ov1.x = smf[rr*SF + cc + 4] + rv1.x;
            ov1.y = smf[rr*SF + cc + 5] + rv1.y;
            ov1.z = smf[rr*SF + cc + 6] + rv1.z;
            ov1.w = smf[rr*SF + cc + 7] + rv1.w;
            *(float4*)&C[gro]     = ov0;
            *(float4*)&C[gro + 4] = ov1;
        }
    }
}

extern "C" void kernel_launch(void* const* d_in, const int* in_sizes, int n_in,
                              void* d_out, int out_size, void* d_ws, size_t ws_size,
                              hipStream_t stream) {
    (void)in_sizes; (void)n_in; (void)out_size; (void)ws_size;
    const float* x     = (const float*)d_in[0];
    const float* gn_w  = (const float*)d_in[1];
    const float* gn_b  = (const float*)d_in[2];
    const float* qkv_w = (const float*)d_in[3];
    const float* qkv_b = (const float*)d_in[4];
    const float* out_w = (const float*)d_in[5];
    const float* out_b = (const float*)d_in[6];
    float* out = (float*)d_out;

    char* ws = (char*)d_ws;
    u16*  h_t   = (u16*)ws;  ws += (size_t)16*1024*512*2;    // 16 MB h[b][n][c]
    u16*  qkv_t = (u16*)ws;  ws += (size_t)16*1024*1536*2;   // 48 MB qkv[b*n][1536] (q|k|v)
    u16*  vprm  = (u16*)ws;  ws += (size_t)512*16384*2;      // 16 MB V' = (Wo V^T) : [c_out][b*1024+n]
    u16*  S     = (u16*)ws;  ws += (size_t)16*1024*1024*2;   // 32 MB S/P[b][n][m]
    u16*  wq    = (u16*)ws;  ws += (size_t)1536*512*2;
    u16*  wo    = (u16*)ws;  ws += (size_t)512*512*2;

    wconv_kernel<<<1024, 256, 0, stream>>>(qkv_w, wq, out_w, wo);
    gn_fused_kernel<<<512, 256, 0, stream>>>(x, gn_w, gn_b, h_t);

    // QKV: M=1536, Nn=16384, K=512 ; all transposed -> qkv_t[bn][1536] + bias
    gemm_bt_kernel<2, 0, 0><<<dim3(128, 12, 1), 256, 0, stream>>>(
        wq, h_t, qkv_t, qkv_b, nullptr, 1.0f,
        512, 512, 1536, 0, 0, 0, 0, 512);

    // V' = Wo @ V^T : M=512(c_out), Nn=16384(bn), K=512(c_in)
    gemm_bt_kernel<1, 0, 0><<<dim3(128, 4, 1), 256, 0, stream>>>(
        wo, qkv_t + 1024, vprm, nullptr, nullptr, 1.0f,
        512, 1536, 16384, 0, 0, 0, 0, 512);

    // S = q k^T * scale : per batch M=Nn=1024, K=512 ; XCD-affine (z&7)
    gemm_bt_kernel<1, 8, 8><<<1024, 256, 0, stream>>>(
        qkv_t, qkv_t + 512, S, nullptr, nullptr, 0.044194173824159216f,
        1536, 1536, 1024,
        (long long)1024*1536, (long long)1024*1536, (long long)1024*1024, 0, 512);

    softmax_kernel<<<4096, 256, 0, stream>>>(S);

    // out = vprm ⊗ P + out_b + x : M=512(c_out), Nn=1024(n), K=1024 ; XCD-affine
    gemm_bt_kernel<0, 8, 4><<<512, 256, 0, stream>>>(
        vprm, S, out, out_b, x, 1.0f,
        16384, 1024, 1024,
        1024, (long long)1024*1024, (long long)512*1024, (long long)512*1024, 1024);
}